// Round 1
// baseline (676.163 us; speedup 1.0000x reference)
//
#include <hip/hip_runtime.h>

// Correlation layer (FlowNet-style), max_displacement=4.
// in1,in2: [8,256,128,128] fp32 -> out: [8,81,128,128] fp32
// out[b, dy*9+dx, y, x] = sum_c in1[b,c,y,x] * in2[b,c,y+dy-4,x+dx-4] (0 if OOB)

constexpr int Bn = 8, Cn = 256, Hn = 128, Wn = 128;
constexpr int Dd = 4, ND = 9;          // 9 displacements per axis
constexpr int KC = 8;                  // channels staged per chunk
constexpr int NT = 576;                // 9 waves: dy(9) x 64 lanes (2 px each)
constexpr int W2 = Wn + 8;             // padded in2 row width (136)

__global__ __launch_bounds__(NT) void corr_kernel(
    const float* __restrict__ in1, const float* __restrict__ in2,
    float* __restrict__ out)
{
  __shared__ float s1[KC][2][Wn];      // 8 KB   : in1 row-pair
  __shared__ float s2[KC][10][W2];     // 43.5 KB: in2 rows y0-4 .. y0+5, x-padded by 4

  // XCD-chunked swizzle: 512 blocks, 8 XCDs -> 64 consecutive y-pair blocks
  // (= one full batch) per XCD for L2 locality. 512 % 8 == 0, bijective.
  int bid = blockIdx.x;
  bid = (bid & 7) * 64 + (bid >> 3);
  const int b  = bid >> 6;             // batch
  const int y0 = (bid & 63) << 1;      // output row pair y0, y0+1

  const int tid  = threadIdx.x;
  const int dy   = tid >> 6;           // 0..8
  const int lane = tid & 63;
  const int x0   = lane << 1;          // 2 consecutive x per thread

  float acc[2][2][ND];
#pragma unroll
  for (int yy = 0; yy < 2; ++yy)
#pragma unroll
    for (int xc = 0; xc < 2; ++xc)
#pragma unroll
      for (int dx = 0; dx < ND; ++dx) acc[yy][xc][dx] = 0.f;

  const size_t base = (size_t)b * Cn * Hn * Wn;

  for (int c0 = 0; c0 < Cn; c0 += KC) {
    // ---- stage in1: KC*2*128 = 2048 elements ----
    for (int i = tid; i < KC * 2 * Wn; i += NT) {
      const int kc  = i >> 8;          // / 256
      const int rem = i & 255;
      const int yy  = rem >> 7;
      const int x   = rem & 127;
      s1[kc][yy][x] =
          in1[base + (size_t)(c0 + kc) * (Hn * Wn) + (y0 + yy) * Wn + x];
    }
    // ---- stage in2: KC*10*136 = 10880 elements (zero-padded halo) ----
    for (int i = tid; i < KC * 10 * W2; i += NT) {
      const int kc  = i / (10 * W2);
      int       rem = i - kc * (10 * W2);
      const int r   = rem / W2;
      const int xx  = rem - r * W2;
      const int gy  = y0 + r - Dd;     // global y of staged row
      const int gx  = xx - Dd;         // global x of staged col
      float v = 0.f;
      if ((unsigned)gy < (unsigned)Hn && (unsigned)gx < (unsigned)Wn)
        v = in2[base + (size_t)(c0 + kc) * (Hn * Wn) + gy * Wn + gx];
      s2[kc][r][xx] = v;
    }
    __syncthreads();

#pragma unroll
    for (int kc = 0; kc < KC; ++kc) {
      const float2 a0 = *(const float2*)&s1[kc][0][x0];
      const float2 a1 = *(const float2*)&s1[kc][1][x0];
      float b0[10], b1[10];
#pragma unroll
      for (int j = 0; j < 5; ++j) {
        *(float2*)&b0[2 * j] = *(const float2*)&s2[kc][dy    ][x0 + 2 * j];
        *(float2*)&b1[2 * j] = *(const float2*)&s2[kc][dy + 1][x0 + 2 * j];
      }
#pragma unroll
      for (int dx = 0; dx < ND; ++dx) {
        acc[0][0][dx] += a0.x * b0[dx];
        acc[0][1][dx] += a0.y * b0[dx + 1];
        acc[1][0][dx] += a1.x * b1[dx];
        acc[1][1][dx] += a1.y * b1[dx + 1];
      }
    }
    __syncthreads();
  }

  // ---- epilogue: coalesced float2 stores ----
#pragma unroll
  for (int yy = 0; yy < 2; ++yy) {
#pragma unroll
    for (int dx = 0; dx < ND; ++dx) {
      const size_t o =
          (((size_t)b * (ND * ND) + dy * ND + dx) * Hn + (y0 + yy)) * Wn + x0;
      float2 v;
      v.x = acc[yy][0][dx];
      v.y = acc[yy][1][dx];
      *(float2*)&out[o] = v;
    }
  }
}

extern "C" void kernel_launch(void* const* d_in, const int* in_sizes, int n_in,
                              void* d_out, int out_size, void* d_ws, size_t ws_size,
                              hipStream_t stream) {
  const float* in1 = (const float*)d_in[0];
  const float* in2 = (const float*)d_in[1];
  float* out = (float*)d_out;
  dim3 grid(Bn * (Hn / 2));   // 512 blocks: (batch, y-pair)
  dim3 block(NT);             // 576 threads = 9 waves
  hipLaunchKernelGGL(corr_kernel, grid, block, 0, stream, in1, in2, out);
}

// Round 3
// 111.031 us; speedup vs baseline: 6.0899x; 6.0899x over previous
//
#include <hip/hip_runtime.h>

// Correlation layer (FlowNet-style), max_displacement=4.
// in1,in2: [8,256,128,128] fp32 -> out: [8,81,128,128] fp32
// out[b, dy*9+dx, y, x] = sum_c in1[b,c,y,x] * in2[b,c,y+dy-4,x+dx-4] (0 if OOB)
//
// Round-2 structure: f16x2 channel-pair packing + v_dot2_f32_f16 (2 MAC/op,
// fp32 accumulate), 4 px per lane with ds_read_b128, vectorized staging.

constexpr int Bn = 8, Cn = 256, Hn = 128, Wn = 128, HW = Hn * Wn;
constexpr int Dd = 4, ND = 9;
constexpr int KC = 16;                 // channels per chunk (8 f16x2 pairs)
constexpr int NP = KC / 2;             // 8 pairs
constexpr int NT = 576;                // 9 waves: dy(9) x (2 rows x 32 lane-groups of 4 px)
constexpr int W2 = Wn + 8;             // padded in2 row width in pairs (136)

typedef __fp16 h2v __attribute__((ext_vector_type(2)));

static __device__ __forceinline__ unsigned packh2(float a, float b) {
  h2v h = __builtin_amdgcn_cvt_pkrtz(a, b);   // a->low, b->high
  return __builtin_bit_cast(unsigned, h);
}

static __device__ __forceinline__ float dot2(unsigned a, unsigned b, float c) {
#if __has_builtin(__builtin_amdgcn_fdot2)
  return __builtin_amdgcn_fdot2(__builtin_bit_cast(h2v, a),
                                __builtin_bit_cast(h2v, b), c, false);
#else
  h2v ha = __builtin_bit_cast(h2v, a), hb = __builtin_bit_cast(h2v, b);
  return c + (float)ha.x * (float)hb.x + (float)ha.y * (float)hb.y;
#endif
}

__global__ __launch_bounds__(NT) void corr_kernel(
    const float* __restrict__ in1, const float* __restrict__ in2,
    float* __restrict__ out)
{
  // u32 = one f16x2 channel-pair
  __shared__ __align__(16) unsigned s1h[NP][2][Wn];    // 8 KB
  __shared__ __align__(16) unsigned s2h[NP][10][W2];   // 42.5 KB

  // XCD-chunked swizzle: 512 blocks, 8 XCDs, bijective (512 % 8 == 0).
  int bid = blockIdx.x;
  bid = (bid & 7) * 64 + (bid >> 3);
  const int b  = bid >> 6;
  const int y0 = (bid & 63) << 1;

  const int tid  = threadIdx.x;
  const int dy   = tid >> 6;           // 0..8 (wave id)
  const int lane = tid & 63;
  const int row  = lane >> 5;          // 0..1
  const int xq   = (lane & 31) << 2;   // 4 consecutive px

  const size_t base = (size_t)b * Cn * HW;

  // Zero s2h once: x-halo cols [0..3] and [132..135] (always zero) are
  // written ONLY here; interior + OOB rows are rewritten every chunk.
  for (int i = tid * 4; i < NP * 10 * W2; i += NT * 4)
    *(uint4*)(&s2h[0][0][0] + i) = uint4{0, 0, 0, 0};

  float4 acc[ND];
#pragma unroll
  for (int dx = 0; dx < ND; ++dx) acc[dx] = float4{0.f, 0.f, 0.f, 0.f};

  const int srow = dy + row;

  for (int c0 = 0; c0 < Cn; c0 += KC) {
    __syncthreads();                   // first iter: orders zero-init vs staging

    // ---- stage in1: NP*2*32 = 512 float4-groups ----
    for (int i = tid; i < NP * 2 * 32; i += NT) {
      const int p  = i >> 6;
      const int yy = (i >> 5) & 1;
      const int gx = (i & 31) << 2;
      const float* s = in1 + base + (size_t)(c0 + 2 * p) * HW + (y0 + yy) * Wn + gx;
      const float4 f0 = *(const float4*)s;
      const float4 f1 = *(const float4*)(s + HW);
      uint4 w;
      w.x = packh2(f0.x, f1.x); w.y = packh2(f0.y, f1.y);
      w.z = packh2(f0.z, f1.z); w.w = packh2(f0.w, f1.w);
      *(uint4*)&s1h[p][yy][gx] = w;
    }

    // ---- stage in2: NP*10*32 = 2560 float4-groups (interior cols only) ----
    for (int i = tid; i < NP * 10 * 32; i += NT) {
      const int p   = i / 320;
      const int rem = i - p * 320;
      const int r   = rem >> 5;
      const int gx  = (rem & 31) << 2;
      const int gy  = y0 + r - Dd;
      const bool ok = (unsigned)gy < (unsigned)Hn;
      const int gyc = ok ? gy : 0;
      const float* s = in2 + base + (size_t)(c0 + 2 * p) * HW + (size_t)gyc * Wn + gx;
      const float4 f0 = *(const float4*)s;
      const float4 f1 = *(const float4*)(s + HW);
      uint4 w;
      w.x = packh2(f0.x, f1.x); w.y = packh2(f0.y, f1.y);
      w.z = packh2(f0.z, f1.z); w.w = packh2(f0.w, f1.w);
      if (!ok) w = uint4{0, 0, 0, 0};
      *(uint4*)&s2h[p][r][4 + gx] = w;
    }
    __syncthreads();

    // ---- compute: per pair 4x ds_read_b128 -> 36 dot2 (72 MACs) ----
#pragma unroll
    for (int kc = 0; kc < NP; ++kc) {
      const unsigned* bp = &s2h[kc][srow][xq];
      const uint4 b0 = *(const uint4*)bp;
      const uint4 b1 = *(const uint4*)(bp + 4);
      const uint4 b2 = *(const uint4*)(bp + 8);
      const uint4 av = *(const uint4*)&s1h[kc][row][xq];
      const unsigned bb[12] = {b0.x, b0.y, b0.z, b0.w, b1.x, b1.y,
                               b1.z, b1.w, b2.x, b2.y, b2.z, b2.w};
      const unsigned aa[4] = {av.x, av.y, av.z, av.w};
#pragma unroll
      for (int dx = 0; dx < ND; ++dx) {
        acc[dx].x = dot2(aa[0], bb[0 + dx], acc[dx].x);
        acc[dx].y = dot2(aa[1], bb[1 + dx], acc[dx].y);
        acc[dx].z = dot2(aa[2], bb[2 + dx], acc[dx].z);
        acc[dx].w = dot2(aa[3], bb[3 + dx], acc[dx].w);
      }
    }
  }

  // ---- epilogue: coalesced float4 stores ----
#pragma unroll
  for (int dx = 0; dx < ND; ++dx) {
    const size_t o =
        (((size_t)b * (ND * ND) + dy * ND + dx) * Hn + (y0 + row)) * Wn + xq;
    *(float4*)&out[o] = acc[dx];
  }
}

extern "C" void kernel_launch(void* const* d_in, const int* in_sizes, int n_in,
                              void* d_out, int out_size, void* d_ws, size_t ws_size,
                              hipStream_t stream) {
  const float* in1 = (const float*)d_in[0];
  const float* in2 = (const float*)d_in[1];
  float* out = (float*)d_out;
  dim3 grid(Bn * (Hn / 2));   // 512 blocks: (batch, y-pair)
  dim3 block(NT);             // 576 threads = 9 waves
  hipLaunchKernelGGL(corr_kernel, grid, block, 0, stream, in1, in2, out);
}